// Round 8
// baseline (304.875 us; speedup 1.0000x reference)
//
#include <hip/hip_runtime.h>

#define B_   32
#define L_   200
#define DIM_ 36
#define ET_  128
#define NH_  64
#define SD_  9
#define NC_  2

// element offsets within d_out (float32)
#define O_TE   0
#define O_T1   147456
#define O_LG   294912
#define O_SXG  294976
#define O_SOUT 336448
#define O_QP   377920

typedef __fp16 half_t;
typedef __attribute__((ext_vector_type(2))) __fp16 half2_t;

__device__ __forceinline__ float sigm(float x) { return 1.f / (1.f + expf(-x)); }
__device__ __forceinline__ float fsigm(float x) {
  return __builtin_amdgcn_rcpf(1.f + __expf(-x));
}
__device__ __forceinline__ float ftanh(float x) {
  return 2.f * __builtin_amdgcn_rcpf(1.f + __expf(-2.f * x)) - 1.f;
}
__device__ __forceinline__ half2_t f2h2(float a, float b) {
  return __builtin_amdgcn_cvt_pkrtz(a, b);
}
__device__ __forceinline__ float dot2acc(half2_t w, half2_t h, float acc) {
#if __has_builtin(__builtin_amdgcn_fdot2)
  return __builtin_amdgcn_fdot2(w, h, acc, false);
#else
  return acc + (float)w.x * (float)h.x + (float)w.y * (float)h.y;
#endif
}

// ---------------------------------------------------------------------------
// K1 (k_pre2 v3, R7 exact): blocks 0..127 qm2; 128..159 xmean; 160..223
// ks_emb pre-swizzled; 224..255 W f16.
__global__ __launch_bounds__(256) void k_pre2(
    const float* __restrict__ qw, const float* __restrict__ kw,
    const float* __restrict__ qb, const float* __restrict__ qp,
    const float* __restrict__ pw, const float* __restrict__ pb,
    const float* __restrict__ tlw, const float* __restrict__ tlb,
    const float* __restrict__ ts, const float* __restrict__ x,
    const int* __restrict__ rm,
    float* __restrict__ qm2, float* __restrict__ xmean,
    float* __restrict__ ks_ws, half2_t* __restrict__ w_ws,
    float* __restrict__ out) {
  int blk = blockIdx.x, t = threadIdx.x;
  if (blk < 128) {
    __shared__ float eq[128];
    __shared__ float uq[128];
    int q = blk;
    if (t < 128) {
      float tt = qp[q];
      eq[t] = (t == 0) ? tt * tlw[0] + tlb[0]
                       : __sinf(tt * pw[t - 1] + pb[t - 1]);
    }
    __syncthreads();
    if (t < 128) {
      const float4* qw4 = (const float4*)(qw + (size_t)t * 128);
      float a = qb[t];
      #pragma unroll 8
      for (int c = 0; c < 32; c++) {
        float4 w = qw4[c];
        a += eq[4 * c] * w.x + eq[4 * c + 1] * w.y +
             eq[4 * c + 2] * w.z + eq[4 * c + 3] * w.w;
      }
      uq[t] = a;
    }
    __syncthreads();
    if (t < 128) {
      float a = 0.f;
      #pragma unroll 8
      for (int i = 0; i < 128; i++) a += uq[i] * kw[i * 128 + t];
      qm2[q * 128 + t] = a * 0.088388347648318447f;
      if (q == 0) out[O_QP + t] = qp[t];
    }
    return;
  }
  if (blk < 160) {
    int b = blk - 128;
    if (t < 72) {
      float s = 0.f;
      const float* xb = x + (size_t)b * L_ * 72 + t;
      #pragma unroll 8
      for (int l = 0; l < L_; l++) s += xb[(size_t)l * 72];
      xmean[b * 72 + t] = s * (1.0f / L_);
    }
    return;
  }
  if (blk < 224) {
    int bb = (blk - 160) >> 1, half = (blk - 160) & 1;
    float tl_w = tlw[0], tl_b = tlb[0];
    const float* tsb = ts + bb * L_;
    float* dst = ks_ws + (size_t)bb * 25600;
    for (int i = half * 12800 + t; i < half * 12800 + 12800; i += 256) {
      int l = i >> 7, j = i & 127;
      float tt = tsb[l];
      float e = (j == 0) ? tt * tl_w + tl_b
                         : __sinf(tt * pw[j - 1] + pb[j - 1]);
      int blkj = (j >> 2) ^ ((l >> 2) & 7);
      dst[(l << 7) + (blkj << 2) + (j & 3)] = e;
    }
    return;
  }
  {
    int bb = blk - 224;
    const float2* xb2 = (const float2*)(x + (size_t)bb * L_ * 72);
    const int* rmb = rm + bb * L_;
    half2_t* wd = w_ws + (size_t)bb * 14400;
    for (int i = t; i < L_ * 72; i += 256) {
      int l = i / 72, c2 = i % 72;
      int seg = c2 / 18, fh = c2 % 18;
      float2 v = xb2[l * 36 + fh];
      float2 o = xb2[l * 36 + 18 + fh];
      float rr = (float)rmb[l];
      float w0, w1;
      if (seg == 0)      { w0 = o.x * v.x;      w1 = o.y * v.y; }
      else if (seg == 1) { w0 = o.x;            w1 = o.y; }
      else if (seg == 2) { w0 = o.x * v.x * rr; w1 = o.y * v.y * rr; }
      else               { w0 = o.x * rr;       w1 = o.y * rr; }
      wd[l * 72 + c2] = f2h2(w0, w1);
    }
  }
}

// ---------------------------------------------------------------------------
// K2 (k_attn v7, R7 exact): 16-q structure; P0/P4 are float4 copies from
// the precomputed ks_ws (swizzled f32) and w_ws (f16) tensors.
__global__ __launch_bounds__(1024, 1) void k_attn(
    const float* __restrict__ qm, const float* __restrict__ ks_ws,
    const half2_t* __restrict__ w_ws,
    const float* __restrict__ xmean, const float* __restrict__ ow,
    const float* __restrict__ ob, float* __restrict__ out) {
  __shared__ __align__(16) char Abuf[103936];   // ks (f32 swz) / wsh2+sums+ofr
  __shared__ __align__(16) float qs[16][128];
  __shared__ __align__(16) float sc[16][200];
  __shared__ __align__(16) float owsh[DIM_][72];
  float*   ksA  = (float*)Abuf;                       // [200][128] swizzled
  half2_t* wsh2 = (half2_t*)Abuf;                     // [200][72] f16x2
  float*   sums = (float*)(Abuf + 57600);             // [4][16][144] partials
  float*   ofr  = (float*)(Abuf + 57600 + 36864);     // [16][144]

  int b = blockIdx.x >> 3;
  int q0 = (blockIdx.x & 7) << 4;
  int tid = threadIdx.x;

  // P0: stage q-tile, ow, and COPY pre-swizzled key embeddings
  const float4* qsrc = (const float4*)(qm + q0 * ET_);
  for (int i = tid; i < 16 * 32; i += 1024) ((float4*)qs)[i] = qsrc[i];
  const float4* owsrc = (const float4*)ow;
  for (int i = tid; i < DIM_ * 18; i += 1024) ((float4*)owsh)[i] = owsrc[i];
  {
    const float4* kssrc = (const float4*)(ks_ws + (size_t)b * 25600);
    for (int i = tid; i < 6400; i += 1024) ((float4*)ksA)[i] = kssrc[i];
  }
  __syncthreads();

  // P2: scores -- 16 waves = 8 q-pairs x 2 l-halves; 2 l per lane
  {
    int w = tid >> 6, lg = tid & 63;
    int qp2 = w >> 1;
    int lh = w & 1;
    float acc[2][2];
    #pragma unroll
    for (int i = 0; i < 2; i++)
      #pragma unroll
      for (int j = 0; j < 2; j++) acc[i][j] = 0.f;
    const float4* ks4 = (const float4*)ksA;
    const float4* qs4 = (const float4*)qs;
    int lbase = 100 * lh + 2 * lg;
    int swz0 = (lbase >> 2) & 7;
    int swz1 = ((lbase + 1) >> 2) & 7;
    #pragma unroll 4
    for (int d4 = 0; d4 < 32; d4++) {
      float4 kv[2];
      {
        int l0c = (lbase < 100 * lh + 100) ? lbase : (100 * lh + 99);
        int l1c = (lbase + 1 < 100 * lh + 100) ? lbase + 1 : (100 * lh + 99);
        kv[0] = ks4[(l0c << 5) + (d4 ^ swz0)];
        kv[1] = ks4[(l1c << 5) + (d4 ^ swz1)];
      }
      #pragma unroll
      for (int i = 0; i < 2; i++) {
        float4 qv = qs4[(2 * qp2 + i) * 32 + d4];
        #pragma unroll
        for (int j = 0; j < 2; j++)
          acc[i][j] += qv.x * kv[j].x + qv.y * kv[j].y +
                       qv.z * kv[j].z + qv.w * kv[j].w;
      }
    }
    if (2 * lg < 100) {
      #pragma unroll
      for (int i = 0; i < 2; i++) {
        float2 v = {acc[i][0], acc[i][1]};
        *((float2*)(&sc[2 * qp2 + i][lbase])) = v;
      }
    }
  }
  __syncthreads();

  // P3: rowmax + exp in place (64 lanes per q-row)
  {
    int qi = tid >> 6, li = tid & 63;
    float m = -1e30f;
    for (int l = li; l < L_; l += 64) m = fmaxf(m, sc[qi][l]);
    #pragma unroll
    for (int off = 32; off >= 1; off >>= 1) m = fmaxf(m, __shfl_xor(m, off));
    for (int l = li; l < L_; l += 64) sc[qi][l] = __expf(sc[qi][l] - m);
  }

  // P4: COPY precomputed W f16 into the (dead) ks region
  {
    const float4* wsrc = (const float4*)(w_ws + (size_t)b * 14400);
    for (int i = tid; i < 3600; i += 1024) ((float4*)wsh2)[i] = wsrc[i];
  }
  __syncthreads();

  // P5: weight sums, l split 4 ways (partials in sums[4][16][144])
  {
    int quarter = tid >> 8, tt = tid & 255;
    int qi = tt >> 4, li = tt & 15;
    int l0 = quarter * 50;
    float accA[8], accB[8];
    #pragma unroll
    for (int k = 0; k < 8; k++) { accA[k] = 0.f; accB[k] = 0.f; }
    const float4* wA = (const float4*)wsh2;
    #pragma unroll 2
    for (int l = l0; l < l0 + 50; l++) {
      float ev = sc[qi][l];
      float4 wa = wA[l * 18 + li];
      union { float f; half2_t h; } u0, u1, u2, u3;
      u0.f = wa.x; u1.f = wa.y; u2.f = wa.z; u3.f = wa.w;
      accA[0] += ev * (float)u0.h.x; accA[1] += ev * (float)u0.h.y;
      accA[2] += ev * (float)u1.h.x; accA[3] += ev * (float)u1.h.y;
      accA[4] += ev * (float)u2.h.x; accA[5] += ev * (float)u2.h.y;
      accA[6] += ev * (float)u3.h.x; accA[7] += ev * (float)u3.h.y;
      if (li < 2) {
        float4 wb = wA[l * 18 + 16 + li];
        union { float f; half2_t h; } b0, b1, b2, b3;
        b0.f = wb.x; b1.f = wb.y; b2.f = wb.z; b3.f = wb.w;
        accB[0] += ev * (float)b0.h.x; accB[1] += ev * (float)b0.h.y;
        accB[2] += ev * (float)b1.h.x; accB[3] += ev * (float)b1.h.y;
        accB[4] += ev * (float)b2.h.x; accB[5] += ev * (float)b2.h.y;
        accB[6] += ev * (float)b3.h.x; accB[7] += ev * (float)b3.h.y;
      }
    }
    float* sq = sums + quarter * 2304 + qi * 144;
    float4* sA = (float4*)(sq + 8 * li);
    sA[0] = make_float4(accA[0], accA[1], accA[2], accA[3]);
    sA[1] = make_float4(accA[4], accA[5], accA[6], accA[7]);
    if (li < 2) {
      float4* sB = (float4*)(sq + 128 + 8 * li);
      sB[0] = make_float4(accB[0], accB[1], accB[2], accB[3]);
      sB[1] = make_float4(accB[4], accB[5], accB[6], accB[7]);
    }
  }
  __syncthreads();

  // P6: combine quarters + divisions + uniform-mean fallback
  const float* xm = xmean + b * 72;
  for (int idx = tid; idx < 16 * DIM_; idx += 1024) {
    int qq = idx / DIM_, j = idx % DIM_;
    const float* s0 = sums + qq * 144;
    const float* s1 = s0 + 2304;
    const float* s2 = s1 + 2304;
    const float* s3 = s2 + 2304;
    float numA = (s0[j] + s1[j]) + (s2[j] + s3[j]);
    float denA = (s0[36 + j] + s1[36 + j]) + (s2[36 + j] + s3[36 + j]);
    float numB = (s0[72 + j] + s1[72 + j]) + (s2[72 + j] + s3[72 + j]);
    float denB = (s0[108 + j] + s1[108 + j]) + (s2[108 + j] + s3[108 + j]);
    float al, ah, bl, bh;
    if (denA > 0.f) { al = numA / denA; ah = 1.f; }
    else            { al = xm[j];       ah = xm[36 + j]; }
    if (denB > 0.f) { bl = numB / denB; bh = 1.f; }
    else            { bl = xm[j];       bh = xm[36 + j]; }
    float* oq = ofr + qq * 144;
    oq[j] = al;      oq[36 + j] = ah;
    oq[72 + j] = bl; oq[108 + j] = bh;
  }
  __syncthreads();

  // P7: output projection (float4 dots)
  for (int idx = tid; idx < 16 * 72; idx += 1024) {
    int qq = idx / 72, t = idx % 72;
    int v = t / DIM_, i2 = t % DIM_;
    const float4* o4 = (const float4*)(ofr + qq * 144 + v * 72);
    const float4* w4 = (const float4*)(owsh[i2]);
    float a = ob[i2];
    #pragma unroll
    for (int d4 = 0; d4 < 18; d4++) {
      float4 ov = o4[d4], wv = w4[d4];
      a += ov.x * wv.x + ov.y * wv.y + ov.z * wv.z + ov.w * wv.w;
    }
    size_t off = ((size_t)b * ET_ + q0 + qq) * DIM_ + i2;
    out[(v == 0 ? O_TE : O_T1) + off] = a;
  }
}

// ---------------------------------------------------------------------------
// K3 (k_sg v11): blocks 0..31 sout+sxg; blocks 32..47: DUAL-BATCH GRU —
// each wave carries TWO independent scans (b0=2i, b1=2i+1) sharing the same
// whh VGPR weights; the two dependent chains interleave so each hides the
// other's LDS-roundtrip/chain/transcendental latency. b0's gi in LDS (f32),
// b1's gi in global ws (f32, L2-hot, prefetched one iter ahead). Block 48:
// classifier (waits for 16 GRU blocks).
__global__ __launch_bounds__(256, 1) void k_sg(
    const float* __restrict__ out_ro, const float* __restrict__ x,
    const float* __restrict__ wih, const float* __restrict__ bih,
    const float* __restrict__ whh, const float* __restrict__ bhh,
    const float* __restrict__ si, const float* __restrict__ stw,
    const float* __restrict__ stb, const float* __restrict__ c1w,
    const float* __restrict__ c1b, const float* __restrict__ bng,
    const float* __restrict__ bnb, const float* __restrict__ c2w,
    const float* __restrict__ c2b,
    float* __restrict__ hfin, int* __restrict__ ctr,
    float* __restrict__ gi1ws, float* __restrict__ out) {
  __shared__ __align__(16) float ote_s[2][ET_][DIM_];  // 36 KB
  __shared__ float gis[ET_][3 * NH_];                  // 96 KB
  __shared__ __align__(16) half2_t hpk0[NH_ / 2];
  __shared__ __align__(16) half2_t hpk1[NH_ / 2];
  int blk = blockIdx.x, t = threadIdx.x;

  if (blk >= 48) {
    // ---- classifier block ----
    float* base = &gis[0][0];
    float (*cin)[72] = (float(*)[72])(base);              // [32][72]
    float (*z1)[72]  = (float(*)[72])(base + 2304);       // [32][72]
    float (*zg)[72]  = (float(*)[72])(base + 4608);       // [32][72]
    float* c1wt = base + 6912;                            // [72][72] transposed
    float* c2ws = base + 6912 + 5184;                     // [2][72]
    float* bngs = c2ws + 144;                             // [72]
    float* bnbs = bngs + 72;                              // [72]
    for (int idx = t; idx < 72 * 72; idx += 256) {
      int j = idx / 72, d = idx % 72;
      c1wt[d * 72 + j] = c1w[idx];
    }
    for (int idx = t; idx < NC_ * 72; idx += 256) c2ws[idx] = c2w[idx];
    if (t < 72) { bngs[t] = bng[t]; bnbs[t] = bnb[t]; }
    for (int idx = t; idx < B_ * 8; idx += 256) {
      int b = idx / 8, j = idx % 8;
      float acc = stb[j];
      #pragma unroll
      for (int d = 0; d < SD_; d++) acc += si[b * SD_ + d] * stw[j * SD_ + d];
      cin[b][NH_ + j] = acc;
    }
    __syncthreads();
    if (t == 0) {
      while (__hip_atomic_load(ctr, __ATOMIC_ACQUIRE,
                               __HIP_MEMORY_SCOPE_AGENT) < 16)
        __builtin_amdgcn_s_sleep(8);
    }
    __syncthreads();
    for (int idx = t; idx < B_ * NH_; idx += 256)
      cin[idx / NH_][idx % NH_] = hfin[idx];
    __syncthreads();
    for (int idx = t; idx < B_ * 72; idx += 256) {
      int b = idx / 72, j = idx % 72;
      float acc = c1b[j];
      #pragma unroll 8
      for (int d = 0; d < 72; d++) acc += cin[b][d] * c1wt[d * 72 + j];
      z1[b][j] = acc;
    }
    __syncthreads();
    if (t < 72) {
      float mu = 0.f;
      for (int b = 0; b < B_; b++) mu += z1[b][t];
      mu *= (1.f / B_);
      float vv = 0.f;
      for (int b = 0; b < B_; b++) { float d = z1[b][t] - mu; vv += d * d; }
      vv *= (1.f / B_);
      float inv = 1.f / sqrtf(vv + 1e-5f);
      float g = bngs[t], bb = bnbs[t];
      for (int b = 0; b < B_; b++) {
        float zn = (z1[b][t] - mu) * inv * g + bb;
        zg[b][t] = 0.5f * zn * (1.f + erff(zn * 0.70710678118654752f));
      }
    }
    __syncthreads();
    for (int idx = t; idx < B_ * NC_; idx += 256) {
      int b = idx / NC_, c = idx % NC_;
      float acc = c2b[c];
      #pragma unroll 8
      for (int d = 0; d < 72; d++) acc += zg[b][d] * c2ws[c * 72 + d];
      out[O_LG + idx] = acc;
    }
    return;
  }

  if (blk < 32) {
    int b = blk;
    float* sxs = (float*)gis;  // [200][76]
    const float4* osrc = (const float4*)(out_ro + O_TE + (size_t)b * ET_ * DIM_);
    for (int idx = t; idx < ET_ * 9; idx += 256)
      ((float4*)&ote_s[0][0][0])[idx] = osrc[idx];
    const float4* xsrc = (const float4*)(x + (size_t)b * L_ * 72);
    for (int idx = t; idx < L_ * 18; idx += 256) {
      int l = idx / 18, c = idx % 18;
      ((float4*)&sxs[l * 76])[c] = xsrc[idx];
    }
    __syncthreads();
    for (int idx = t; idx < DIM_ * DIM_; idx += 256) {
      int d = idx / DIM_, e = idx % DIM_;
      float s = 0.f;
      #pragma unroll 8
      for (int q = 0; q < ET_; q++) s += ote_s[0][q][d] * ote_s[0][q][e];
      out[O_SOUT + (size_t)b * DIM_ * DIM_ + idx] = sigm(s);
    }
    for (int idx = t; idx < DIM_ * DIM_; idx += 256) {
      int d = idx / DIM_, e = idx % DIM_;
      float s = 0.f;
      #pragma unroll 8
      for (int l = 0; l < L_; l++) s += sxs[l * 76 + d] * sxs[l * 76 + e];
      out[O_SXG + (size_t)b * DIM_ * DIM_ + idx] = rintf(sigm(s));
    }
    return;
  }

  // ---- dual-batch GRU block ----
  int ib = blk - 32;            // 0..15
  int b0 = ib * 2, b1 = b0 + 1;
  const float* ote = out_ro + O_TE;
  {
    const float4* o0 = (const float4*)(ote + (size_t)b0 * ET_ * DIM_);
    const float4* o1 = (const float4*)(ote + (size_t)b1 * ET_ * DIM_);
    for (int idx = t; idx < ET_ * 9; idx += 256) {
      ((float4*)&ote_s[0][0][0])[idx] = o0[idx];
      ((float4*)&ote_s[1][0][0])[idx] = o1[idx];
    }
  }
  __syncthreads();

  float* gi1 = gi1ws + (size_t)ib * ET_ * 192;

  // phase 1 (both batches): gi[q][t] = bih[t] (+bhh for r/z) + ote[q]·wih[t]
  if (t < 3 * NH_) {
    float wv[DIM_];
    const float* wrow = wih + (size_t)t * DIM_;
    #pragma unroll
    for (int d = 0; d < DIM_; d++) wv[d] = wrow[d];
    float bi = bih[t] + ((t < 2 * NH_) ? bhh[t] : 0.f);
    for (int q = 0; q < ET_; q++) {
      const float4* xr0 = (const float4*)ote_s[0][q];
      const float4* xr1 = (const float4*)ote_s[1][q];
      float a0 = bi, a1 = bi;
      #pragma unroll
      for (int c = 0; c < 9; c++) {
        float4 x0 = xr0[c], x1 = xr1[c];
        a0 += x0.x * wv[4 * c] + x0.y * wv[4 * c + 1] +
              x0.z * wv[4 * c + 2] + x0.w * wv[4 * c + 3];
        a1 += x1.x * wv[4 * c] + x1.y * wv[4 * c + 1] +
              x1.z * wv[4 * c + 2] + x1.w * wv[4 * c + 3];
      }
      gis[q][t] = a0;
      gi1[q * 192 + t] = a1;
    }
  }
  __syncthreads();   // orders LDS + global writes within the block
  if (t >= 64) return;  // waves 1..3 exit; wave 0 scans barrier-free

  // pack whh rows t, 64+t, 128+t into f16 (shared by both batches)
  half2_t wr[32], wz[32], wn[32];
  {
    const float2* r0 = (const float2*)(whh + (size_t)t * NH_);
    const float2* r1 = (const float2*)(whh + (size_t)(NH_ + t) * NH_);
    const float2* r2 = (const float2*)(whh + (size_t)(2 * NH_ + t) * NH_);
    #pragma unroll
    for (int c = 0; c < 32; c++) {
      float2 a = r0[c], bb = r1[c], cc = r2[c];
      wr[c] = f2h2(a.x, a.y);
      wz[c] = f2h2(bb.x, bb.y);
      wn[c] = f2h2(cc.x, cc.y);
    }
  }
  float bh_n = bhh[2 * NH_ + t];

  float h0 = 0.f, h1 = 0.f;
  ((half_t*)hpk0)[t] = (half_t)0.f;
  ((half_t*)hpk1)[t] = (half_t)0.f;
  float gr1 = gi1[t], gz1 = gi1[NH_ + t], gn1 = gi1[2 * NH_ + t];
  for (int q = 0; q < ET_; q++) {
    // prefetch next-iter b1 gi from global (L2-hot; hidden under the dots)
    float gr1n = 0.f, gz1n = 0.f, gn1n = 0.f;
    if (q + 1 < ET_) {
      const float* gp = gi1 + (q + 1) * 192;
      gr1n = gp[t]; gz1n = gp[NH_ + t]; gn1n = gp[2 * NH_ + t];
    }
    float gr0 = gis[q][t];
    float gz0 = gis[q][NH_ + t];
    float gn0 = gis[q][2 * NH_ + t];
    float ar0 = 0.f, az0 = 0.f, an0 = 0.f;
    float ar1 = 0.f, az1 = 0.f, an1 = 0.f;
    const float4* hp40 = (const float4*)hpk0;
    const float4* hp41 = (const float4*)hpk1;
    #pragma unroll
    for (int c4 = 0; c4 < 8; c4++) {
      float4 hv0 = hp40[c4];
      float4 hv1 = hp41[c4];
      union { float f; half2_t h; } a0, a1_, a2, a3, b0_, b1_, b2_, b3_;
      a0.f = hv0.x; a1_.f = hv0.y; a2.f = hv0.z; a3.f = hv0.w;
      b0_.f = hv1.x; b1_.f = hv1.y; b2_.f = hv1.z; b3_.f = hv1.w;
      int c = c4 * 4;
      ar0 = dot2acc(wr[c + 0], a0.h, ar0);
      ar1 = dot2acc(wr[c + 0], b0_.h, ar1);
      az0 = dot2acc(wz[c + 0], a0.h, az0);
      az1 = dot2acc(wz[c + 0], b0_.h, az1);
      an0 = dot2acc(wn[c + 0], a0.h, an0);
      an1 = dot2acc(wn[c + 0], b0_.h, an1);
      ar0 = dot2acc(wr[c + 1], a1_.h, ar0);
      ar1 = dot2acc(wr[c + 1], b1_.h, ar1);
      az0 = dot2acc(wz[c + 1], a1_.h, az0);
      az1 = dot2acc(wz[c + 1], b1_.h, az1);
      an0 = dot2acc(wn[c + 1], a1_.h, an0);
      an1 = dot2acc(wn[c + 1], b1_.h, an1);
      ar0 = dot2acc(wr[c + 2], a2.h, ar0);
      ar1 = dot2acc(wr[c + 2], b2_.h, ar1);
      az0 = dot2acc(wz[c + 2], a2.h, az0);
      az1 = dot2acc(wz[c + 2], b2_.h, az1);
      an0 = dot2acc(wn[c + 2], a2.h, an0);
      an1 = dot2acc(wn[c + 2], b2_.h, an1);
      ar0 = dot2acc(wr[c + 3], a3.h, ar0);
      ar1 = dot2acc(wr[c + 3], b3_.h, ar1);
      az0 = dot2acc(wz[c + 3], a3.h, az0);
      az1 = dot2acc(wz[c + 3], b3_.h, az1);
      an0 = dot2acc(wn[c + 3], a3.h, an0);
      an1 = dot2acc(wn[c + 3], b3_.h, an1);
    }
    float r0 = fsigm(gr0 + ar0);
    float r1 = fsigm(gr1 + ar1);
    float z0 = fsigm(gz0 + az0);
    float z1 = fsigm(gz1 + az1);
    float n0 = ftanh(gn0 + r0 * (an0 + bh_n));
    float n1 = ftanh(gn1 + r1 * (an1 + bh_n));
    h0 = n0 + z0 * (h0 - n0);
    h1 = n1 + z1 * (h1 - n1);
    ((half_t*)hpk0)[t] = (half_t)h0;  // same-wave order: visible next iter
    ((half_t*)hpk1)[t] = (half_t)h1;
    gr1 = gr1n; gz1 = gz1n; gn1 = gn1n;
  }
  hfin[b0 * NH_ + t] = h0;
  hfin[b1 * NH_ + t] = h1;
  __threadfence();                       // release hfin device-wide
  if (t == 0) atomicAdd(ctr, 1);         // device-scope signal to cls block
}

// ---------------------------------------------------------------------------
extern "C" void kernel_launch(void* const* d_in, const int* in_sizes, int n_in,
                              void* d_out, int out_size, void* d_ws,
                              size_t ws_size, hipStream_t stream) {
  const float* x    = (const float*)d_in[0];
  const float* ts   = (const float*)d_in[1];
  const float* si   = (const float*)d_in[2];
  const float* qp   = (const float*)d_in[3];
  const float* pw   = (const float*)d_in[4];
  const float* pb   = (const float*)d_in[5];
  const float* tlw  = (const float*)d_in[6];
  const float* tlb  = (const float*)d_in[7];
  const float* qw   = (const float*)d_in[8];
  const float* qb   = (const float*)d_in[9];
  const float* kw   = (const float*)d_in[10];
  const float* ow   = (const float*)d_in[12];
  const float* ob   = (const float*)d_in[13];
  const float* wih  = (const float*)d_in[14];
  const float* whh  = (const float*)d_in[15];
  const float* bih  = (const float*)d_in[16];
  const float* bhh  = (const float*)d_in[17];
  const float* stw  = (const float*)d_in[18];
  const float* stb  = (const float*)d_in[19];
  const float* c1w  = (const float*)d_in[20];
  const float* c1b  = (const float*)d_in[21];
  const float* bng  = (const float*)d_in[22];
  const float* bnb  = (const float*)d_in[23];
  const float* c2w  = (const float*)d_in[24];
  const float* c2b  = (const float*)d_in[25];
  const int*   rm   = (const int*)d_in[26];

  float* out = (float*)d_out;

  // workspace layout (floats):
  // qm2 16384 | xmean 2304 | hfin 2048 | ctr 64 | ks_ws 819200 |
  // w_ws 460800 (half2) | gi1ws 393216 (16 blocks x 128 x 192)
  float* W = (float*)d_ws;
  float*   ws_qm2   = W;                 // 16384
  float*   ws_xmean = W + 16384;         // 2304
  float*   ws_hfin  = W + 18688;         // 2048
  int*     ws_ctr   = (int*)(W + 20736); // 1 int (padded to 64)
  float*   ws_ks    = W + 20800;         // 819200
  half2_t* ws_w     = (half2_t*)(W + 20800 + 819200);  // 460800 half2
  float*   ws_gi1   = W + 20800 + 819200 + 460800;     // 393216

  hipMemsetAsync(ws_ctr, 0, sizeof(int), stream);
  hipLaunchKernelGGL(k_pre2, dim3(256), dim3(256), 0, stream,
                     qw, kw, qb, qp, pw, pb, tlw, tlb, ts, x, rm,
                     ws_qm2, ws_xmean, ws_ks, ws_w, out);
  hipLaunchKernelGGL(k_attn, dim3(B_ * 8), dim3(1024), 0, stream,
                     ws_qm2, ws_ks, ws_w, ws_xmean, ow, ob, out);
  hipLaunchKernelGGL(k_sg, dim3(49), dim3(256), 0, stream,
                     out, x, wih, bih, whh, bhh, si, stw, stb, c1w, c1b,
                     bng, bnb, c2w, c2b, ws_hfin, ws_ctr, ws_gi1, out);
}

// Round 10
// 235.068 us; speedup vs baseline: 1.2970x; 1.2970x over previous
//
#include <hip/hip_runtime.h>

#define B_   32
#define L_   200
#define DIM_ 36
#define ET_  128
#define NH_  64
#define SD_  9
#define NC_  2

// element offsets within d_out (float32)
#define O_TE   0
#define O_T1   147456
#define O_LG   294912
#define O_SXG  294976
#define O_SOUT 336448
#define O_QP   377920

typedef __fp16 half_t;
typedef __attribute__((ext_vector_type(2))) __fp16 half2_t;

__device__ __forceinline__ float sigm(float x) { return 1.f / (1.f + expf(-x)); }
__device__ __forceinline__ float fsigm(float x) {
  return __builtin_amdgcn_rcpf(1.f + __expf(-x));
}
__device__ __forceinline__ float ftanh(float x) {
  return 2.f * __builtin_amdgcn_rcpf(1.f + __expf(-2.f * x)) - 1.f;
}
__device__ __forceinline__ half2_t f2h2(float a, float b) {
  return __builtin_amdgcn_cvt_pkrtz(a, b);
}
__device__ __forceinline__ float dot2acc(half2_t w, half2_t h, float acc) {
#if __has_builtin(__builtin_amdgcn_fdot2)
  return __builtin_amdgcn_fdot2(w, h, acc, false);
#else
  return acc + (float)w.x * (float)h.x + (float)w.y * (float)h.y;
#endif
}

// ---------------------------------------------------------------------------
// K1 (k_pre2 v3, R7 exact): blocks 0..127 qm2; 128..159 xmean; 160..223
// ks_emb pre-swizzled; 224..255 W f16.
__global__ __launch_bounds__(256) void k_pre2(
    const float* __restrict__ qw, const float* __restrict__ kw,
    const float* __restrict__ qb, const float* __restrict__ qp,
    const float* __restrict__ pw, const float* __restrict__ pb,
    const float* __restrict__ tlw, const float* __restrict__ tlb,
    const float* __restrict__ ts, const float* __restrict__ x,
    const int* __restrict__ rm,
    float* __restrict__ qm2, float* __restrict__ xmean,
    float* __restrict__ ks_ws, half2_t* __restrict__ w_ws,
    float* __restrict__ out) {
  int blk = blockIdx.x, t = threadIdx.x;
  if (blk < 128) {
    __shared__ float eq[128];
    __shared__ float uq[128];
    int q = blk;
    if (t < 128) {
      float tt = qp[q];
      eq[t] = (t == 0) ? tt * tlw[0] + tlb[0]
                       : __sinf(tt * pw[t - 1] + pb[t - 1]);
    }
    __syncthreads();
    if (t < 128) {
      const float4* qw4 = (const float4*)(qw + (size_t)t * 128);
      float a = qb[t];
      #pragma unroll 8
      for (int c = 0; c < 32; c++) {
        float4 w = qw4[c];
        a += eq[4 * c] * w.x + eq[4 * c + 1] * w.y +
             eq[4 * c + 2] * w.z + eq[4 * c + 3] * w.w;
      }
      uq[t] = a;
    }
    __syncthreads();
    if (t < 128) {
      float a = 0.f;
      #pragma unroll 8
      for (int i = 0; i < 128; i++) a += uq[i] * kw[i * 128 + t];
      qm2[q * 128 + t] = a * 0.088388347648318447f;
      if (q == 0) out[O_QP + t] = qp[t];
    }
    return;
  }
  if (blk < 160) {
    int b = blk - 128;
    if (t < 72) {
      float s = 0.f;
      const float* xb = x + (size_t)b * L_ * 72 + t;
      #pragma unroll 8
      for (int l = 0; l < L_; l++) s += xb[(size_t)l * 72];
      xmean[b * 72 + t] = s * (1.0f / L_);
    }
    return;
  }
  if (blk < 224) {
    int bb = (blk - 160) >> 1, half = (blk - 160) & 1;
    float tl_w = tlw[0], tl_b = tlb[0];
    const float* tsb = ts + bb * L_;
    float* dst = ks_ws + (size_t)bb * 25600;
    for (int i = half * 12800 + t; i < half * 12800 + 12800; i += 256) {
      int l = i >> 7, j = i & 127;
      float tt = tsb[l];
      float e = (j == 0) ? tt * tl_w + tl_b
                         : __sinf(tt * pw[j - 1] + pb[j - 1]);
      int blkj = (j >> 2) ^ ((l >> 2) & 7);
      dst[(l << 7) + (blkj << 2) + (j & 3)] = e;
    }
    return;
  }
  {
    int bb = blk - 224;
    const float2* xb2 = (const float2*)(x + (size_t)bb * L_ * 72);
    const int* rmb = rm + bb * L_;
    half2_t* wd = w_ws + (size_t)bb * 14400;
    for (int i = t; i < L_ * 72; i += 256) {
      int l = i / 72, c2 = i % 72;
      int seg = c2 / 18, fh = c2 % 18;
      float2 v = xb2[l * 36 + fh];
      float2 o = xb2[l * 36 + 18 + fh];
      float rr = (float)rmb[l];
      float w0, w1;
      if (seg == 0)      { w0 = o.x * v.x;      w1 = o.y * v.y; }
      else if (seg == 1) { w0 = o.x;            w1 = o.y; }
      else if (seg == 2) { w0 = o.x * v.x * rr; w1 = o.y * v.y * rr; }
      else               { w0 = o.x * rr;       w1 = o.y * rr; }
      wd[l * 72 + c2] = f2h2(w0, w1);
    }
  }
}

// ---------------------------------------------------------------------------
// K2 (k_attn v8b): 512 blocks x 512 threads, 8 q-rows/block, ~62 KB LDS ->
// 2 blocks/CU. All tensors COPIED from precomputed workspace. ksA in two
// [100][128] chunks; W ALSO in two [100][72] chunks (R9 bug: full-W copy
// overran the 28.8KB wsh2 region) with register-carried accumulators.
__global__ __launch_bounds__(512, 4) void k_attn(
    const float* __restrict__ qm, const float* __restrict__ ks_ws,
    const half2_t* __restrict__ w_ws,
    const float* __restrict__ xmean, const float* __restrict__ ow,
    const float* __restrict__ ob, float* __restrict__ out) {
  __shared__ __align__(16) char Abuf[52992];
  __shared__ __align__(16) float qs[8][128];   // 4 KB
  __shared__ __align__(16) float sc[8][200];   // 6.4 KB
  float*   ksA  = (float*)Abuf;                 // [100][128] chunk, 51200 B
  half2_t* wsh2 = (half2_t*)Abuf;               // [100][72] chunk, 28800 B
  float*   sums = (float*)(Abuf + 28800);       // [2][8][144], 9216 B
  float*   ofr  = (float*)(Abuf + 38016);       // [8][144], 4608 B
  float*   owsh = (float*)(Abuf + 42624);       // [36][72], 10368 B

  int b  = blockIdx.x >> 4;
  int q0 = (blockIdx.x & 15) << 3;
  int tid = threadIdx.x;

  // P0: stage q-tile (8 rows)
  {
    const float4* qsrc = (const float4*)(qm + q0 * ET_);
    for (int i = tid; i < 8 * 32; i += 512) ((float4*)qs)[i] = qsrc[i];
  }

  // P1/P2: two ksA chunks, copy + scores
  for (int ck = 0; ck < 2; ck++) {
    const float4* kssrc =
        (const float4*)(ks_ws + (size_t)b * 25600 + ck * 12800);
    for (int i = tid; i < 3200; i += 512) ((float4*)ksA)[i] = kssrc[i];
    __syncthreads();
    {
      int w = tid >> 6, lg = tid & 63;
      int qp2 = w >> 1, lh = w & 1;
      if (lg < 50) {
        int lloc = 50 * lh + lg;            // 0..99 within chunk
        int lglob = ck * 100 + lloc;
        int swz = (lglob >> 2) & 7;         // matches k_pre2's global-l swizzle
        float acc0 = 0.f, acc1 = 0.f;
        const float4* ks4 = (const float4*)ksA;
        const float4* qs4 = (const float4*)qs;
        #pragma unroll 4
        for (int d4 = 0; d4 < 32; d4++) {
          float4 kv = ks4[(lloc << 5) + (d4 ^ swz)];
          float4 qv0 = qs4[(2 * qp2 + 0) * 32 + d4];
          float4 qv1 = qs4[(2 * qp2 + 1) * 32 + d4];
          acc0 += qv0.x * kv.x + qv0.y * kv.y + qv0.z * kv.z + qv0.w * kv.w;
          acc1 += qv1.x * kv.x + qv1.y * kv.y + qv1.z * kv.z + qv1.w * kv.w;
        }
        sc[2 * qp2 + 0][lglob] = acc0;
        sc[2 * qp2 + 1][lglob] = acc1;
      }
    }
    __syncthreads();
  }

  // P3: rowmax + exp in place (64 lanes per q-row) — sc only
  {
    int qi = tid >> 6, li = tid & 63;
    float m = -1e30f;
    for (int l = li; l < L_; l += 64) m = fmaxf(m, sc[qi][l]);
    #pragma unroll
    for (int off = 32; off >= 1; off >>= 1) m = fmaxf(m, __shfl_xor(m, off));
    for (int l = li; l < L_; l += 64) sc[qi][l] = __expf(sc[qi][l] - m);
  }

  // P4/P5: two W chunks (copy from ws) + weight sums, register-carried acc.
  int sub = tid >> 8, tt = tid & 255;
  int qi = tt >> 5, li = tt & 31;
  float accW[8];
  #pragma unroll
  for (int k = 0; k < 8; k++) accW[k] = 0.f;

  for (int ck = 0; ck < 2; ck++) {
    const float4* wsrc =
        (const float4*)(w_ws + (size_t)b * 14400 + ck * 7200);
    for (int i = tid; i < 1800; i += 512) ((float4*)wsh2)[i] = wsrc[i];
    if (ck == 0) {
      const float4* owsrc = (const float4*)ow;
      for (int i = tid; i < DIM_ * 18; i += 512) ((float4*)owsh)[i] = owsrc[i];
    }
    __syncthreads();
    if (li < 18) {
      const float4* wA = (const float4*)wsh2;
      #pragma unroll 2
      for (int l = 0; l < 50; l++) {
        int lW = sub * 50 + l;            // local row within chunk
        float ev = sc[qi][ck * 100 + lW];
        float4 wa = wA[lW * 18 + li];
        union { float f; half2_t h; } u0, u1, u2, u3;
        u0.f = wa.x; u1.f = wa.y; u2.f = wa.z; u3.f = wa.w;
        accW[0] += ev * (float)u0.h.x; accW[1] += ev * (float)u0.h.y;
        accW[2] += ev * (float)u1.h.x; accW[3] += ev * (float)u1.h.y;
        accW[4] += ev * (float)u2.h.x; accW[5] += ev * (float)u2.h.y;
        accW[6] += ev * (float)u3.h.x; accW[7] += ev * (float)u3.h.y;
      }
    }
    __syncthreads();  // all reads of this W chunk done before next copy
  }
  // write sums
  if (li < 18) {
    float* sq = sums + sub * 1152 + qi * 144 + 8 * li;
    ((float4*)sq)[0] = make_float4(accW[0], accW[1], accW[2], accW[3]);
    ((float4*)sq)[1] = make_float4(accW[4], accW[5], accW[6], accW[7]);
  }
  __syncthreads();

  // P6: combine 2 sub-halves + divisions + uniform-mean fallback
  const float* xm = xmean + b * 72;
  for (int idx = tid; idx < 8 * DIM_; idx += 512) {
    int qq = idx / DIM_, j = idx % DIM_;
    const float* s0 = sums + qq * 144;
    const float* s1 = s0 + 1152;
    float numA = s0[j] + s1[j];
    float denA = s0[36 + j] + s1[36 + j];
    float numB = s0[72 + j] + s1[72 + j];
    float denB = s0[108 + j] + s1[108 + j];
    float al, ah, bl, bh;
    if (denA > 0.f) { al = numA / denA; ah = 1.f; }
    else            { al = xm[j];       ah = xm[36 + j]; }
    if (denB > 0.f) { bl = numB / denB; bh = 1.f; }
    else            { bl = xm[j];       bh = xm[36 + j]; }
    float* oq = ofr + qq * 144;
    oq[j] = al;      oq[36 + j] = ah;
    oq[72 + j] = bl; oq[108 + j] = bh;
  }
  __syncthreads();

  // P7: output projection (float4 dots)
  for (int idx = tid; idx < 8 * 72; idx += 512) {
    int qq = idx / 72, t = idx % 72;
    int v = t / DIM_, i2 = t % DIM_;
    const float4* o4 = (const float4*)(ofr + qq * 144 + v * 72);
    const float4* w4 = (const float4*)(owsh + i2 * 72);
    float a = ob[i2];
    #pragma unroll
    for (int d4 = 0; d4 < 18; d4++) {
      float4 ov = o4[d4], wv = w4[d4];
      a += ov.x * wv.x + ov.y * wv.y + ov.z * wv.z + ov.w * wv.w;
    }
    size_t off = ((size_t)b * ET_ + q0 + qq) * DIM_ + i2;
    out[(v == 0 ? O_TE : O_T1) + off] = a;
  }
}

// ---------------------------------------------------------------------------
// K3 (k_sg v10, R5-exact — the scan is FROZEN): blocks 0..31 sout+sxg;
// 32..63 GRU v6 single-scan + release; block 64 classifier with LDS weight
// prefetch hidden under the spin window.
__global__ __launch_bounds__(256, 1) void k_sg(
    const float* __restrict__ out_ro, const float* __restrict__ x,
    const float* __restrict__ wih, const float* __restrict__ bih,
    const float* __restrict__ whh, const float* __restrict__ bhh,
    const float* __restrict__ si, const float* __restrict__ stw,
    const float* __restrict__ stb, const float* __restrict__ c1w,
    const float* __restrict__ c1b, const float* __restrict__ bng,
    const float* __restrict__ bnb, const float* __restrict__ c2w,
    const float* __restrict__ c2b,
    float* __restrict__ hfin, int* __restrict__ ctr,
    float* __restrict__ out) {
  __shared__ __align__(16) float ote_s[ET_][DIM_];  // 18 KB
  __shared__ float gis[ET_][3 * NH_];               // 96 KB (gru/sxg/cls stage)
  __shared__ __align__(16) half2_t hpk[NH_ / 2];    // packed f16 h
  int blk = blockIdx.x, t = threadIdx.x;

  if (blk >= 64) {
    // ---- classifier block ----
    float* base = &gis[0][0];
    float (*cin)[72] = (float(*)[72])(base);              // [32][72]
    float (*z1)[72]  = (float(*)[72])(base + 2304);       // [32][72]
    float (*zg)[72]  = (float(*)[72])(base + 4608);       // [32][72]
    float* c1wt = base + 6912;                            // [72][72] transposed
    float* c2ws = base + 6912 + 5184;                     // [2][72]
    float* bngs = c2ws + 144;                             // [72]
    float* bnbs = bngs + 72;                              // [72]
    for (int idx = t; idx < 72 * 72; idx += 256) {
      int j = idx / 72, d = idx % 72;
      c1wt[d * 72 + j] = c1w[idx];
    }
    for (int idx = t; idx < NC_ * 72; idx += 256) c2ws[idx] = c2w[idx];
    if (t < 72) { bngs[t] = bng[t]; bnbs[t] = bnb[t]; }
    for (int idx = t; idx < B_ * 8; idx += 256) {
      int b = idx / 8, j = idx % 8;
      float acc = stb[j];
      #pragma unroll
      for (int d = 0; d < SD_; d++) acc += si[b * SD_ + d] * stw[j * SD_ + d];
      cin[b][NH_ + j] = acc;
    }
    __syncthreads();
    if (t == 0) {
      while (__hip_atomic_load(ctr, __ATOMIC_ACQUIRE,
                               __HIP_MEMORY_SCOPE_AGENT) < 32)
        __builtin_amdgcn_s_sleep(8);
    }
    __syncthreads();
    for (int idx = t; idx < B_ * NH_; idx += 256)
      cin[idx / NH_][idx % NH_] = hfin[idx];
    __syncthreads();
    for (int idx = t; idx < B_ * 72; idx += 256) {
      int b = idx / 72, j = idx % 72;
      float acc = c1b[j];
      #pragma unroll 8
      for (int d = 0; d < 72; d++) acc += cin[b][d] * c1wt[d * 72 + j];
      z1[b][j] = acc;
    }
    __syncthreads();
    if (t < 72) {
      float mu = 0.f;
      for (int b = 0; b < B_; b++) mu += z1[b][t];
      mu *= (1.f / B_);
      float vv = 0.f;
      for (int b = 0; b < B_; b++) { float d = z1[b][t] - mu; vv += d * d; }
      vv *= (1.f / B_);
      float inv = 1.f / sqrtf(vv + 1e-5f);
      float g = bngs[t], bb = bnbs[t];
      for (int b = 0; b < B_; b++) {
        float zn = (z1[b][t] - mu) * inv * g + bb;
        zg[b][t] = 0.5f * zn * (1.f + erff(zn * 0.70710678118654752f));
      }
    }
    __syncthreads();
    for (int idx = t; idx < B_ * NC_; idx += 256) {
      int b = idx / NC_, c = idx % NC_;
      float acc = c2b[c];
      #pragma unroll 8
      for (int d = 0; d < 72; d++) acc += zg[b][d] * c2ws[c * 72 + d];
      out[O_LG + idx] = acc;
    }
    return;
  }

  if (blk < 32) {
    int b = blk;
    float* sxs = (float*)gis;  // [200][76]
    const float4* osrc = (const float4*)(out_ro + O_TE + (size_t)b * ET_ * DIM_);
    for (int idx = t; idx < ET_ * 9; idx += 256)
      ((float4*)&ote_s[0][0])[idx] = osrc[idx];
    const float4* xsrc = (const float4*)(x + (size_t)b * L_ * 72);
    for (int idx = t; idx < L_ * 18; idx += 256) {
      int l = idx / 18, c = idx % 18;
      ((float4*)&sxs[l * 76])[c] = xsrc[idx];
    }
    __syncthreads();
    for (int idx = t; idx < DIM_ * DIM_; idx += 256) {
      int d = idx / DIM_, e = idx % DIM_;
      float s = 0.f;
      #pragma unroll 8
      for (int q = 0; q < ET_; q++) s += ote_s[q][d] * ote_s[q][e];
      out[O_SOUT + (size_t)b * DIM_ * DIM_ + idx] = sigm(s);
    }
    for (int idx = t; idx < DIM_ * DIM_; idx += 256) {
      int d = idx / DIM_, e = idx % DIM_;
      float s = 0.f;
      #pragma unroll 8
      for (int l = 0; l < L_; l++) s += sxs[l * 76 + d] * sxs[l * 76 + e];
      out[O_SXG + (size_t)b * DIM_ * DIM_ + idx] = rintf(sigm(s));
    }
    return;
  }

  int b = blk - 32;
  const float* ote = out_ro + O_TE;
  const float4* osrc = (const float4*)(ote + (size_t)b * ET_ * DIM_);
  for (int idx = t; idx < ET_ * DIM_ / 4; idx += 256)
    ((float4*)&ote_s[0][0])[idx] = osrc[idx];
  __syncthreads();

  // phase 1: gi[q][t] = bih[t] (+bhh[t] for r/z rows) + ote[q]·wih[t]
  if (t < 3 * NH_) {
    float wv[DIM_];
    const float* wrow = wih + (size_t)t * DIM_;
    #pragma unroll
    for (int d = 0; d < DIM_; d++) wv[d] = wrow[d];
    float bi = bih[t] + ((t < 2 * NH_) ? bhh[t] : 0.f);
    for (int q = 0; q < ET_; q++) {
      const float4* xr = (const float4*)ote_s[q];
      float a = bi;
      #pragma unroll
      for (int c = 0; c < 9; c++) {
        float4 xv = xr[c];
        a += xv.x * wv[4 * c] + xv.y * wv[4 * c + 1] +
             xv.z * wv[4 * c + 2] + xv.w * wv[4 * c + 3];
      }
      gis[q][t] = a;
    }
  }
  __syncthreads();
  if (t >= 64) return;  // waves 1..3 exit; wave 0 scans barrier-free

  // pack whh rows t, 64+t, 128+t into f16 (32 half2 each = 96 VGPRs)
  half2_t wr[32], wz[32], wn[32];
  {
    const float2* r0 = (const float2*)(whh + (size_t)t * NH_);
    const float2* r1 = (const float2*)(whh + (size_t)(NH_ + t) * NH_);
    const float2* r2 = (const float2*)(whh + (size_t)(2 * NH_ + t) * NH_);
    #pragma unroll
    for (int c = 0; c < 32; c++) {
      float2 a = r0[c], bb = r1[c], cc = r2[c];
      wr[c] = f2h2(a.x, a.y);
      wz[c] = f2h2(bb.x, bb.y);
      wn[c] = f2h2(cc.x, cc.y);
    }
  }
  float bh_n = bhh[2 * NH_ + t];

  float h = 0.f;
  ((half_t*)hpk)[t] = (half_t)0.f;
  for (int q = 0; q < ET_; q++) {
    float gi_r = gis[q][t];
    float gi_z = gis[q][NH_ + t];
    float gi_n = gis[q][2 * NH_ + t];
    float ar = 0.f, az = 0.f, an = 0.f;
    const float4* hp4 = (const float4*)hpk;
    #pragma unroll
    for (int c4 = 0; c4 < 8; c4++) {
      float4 hv = hp4[c4];  // broadcast b128 (all lanes same addr)
      union { float f; half2_t h; } u0, u1, u2, u3;
      u0.f = hv.x; u1.f = hv.y; u2.f = hv.z; u3.f = hv.w;
      int c = c4 * 4;
      ar = dot2acc(wr[c + 0], u0.h, ar);
      az = dot2acc(wz[c + 0], u0.h, az);
      an = dot2acc(wn[c + 0], u0.h, an);
      ar = dot2acc(wr[c + 1], u1.h, ar);
      az = dot2acc(wz[c + 1], u1.h, az);
      an = dot2acc(wn[c + 1], u1.h, an);
      ar = dot2acc(wr[c + 2], u2.h, ar);
      az = dot2acc(wz[c + 2], u2.h, az);
      an = dot2acc(wn[c + 2], u2.h, an);
      ar = dot2acc(wr[c + 3], u3.h, ar);
      az = dot2acc(wz[c + 3], u3.h, az);
      an = dot2acc(wn[c + 3], u3.h, an);
    }
    float r = fsigm(gi_r + ar);
    float z = fsigm(gi_z + az);
    float n = ftanh(gi_n + r * (an + bh_n));
    h = n + z * (h - n);
    ((half_t*)hpk)[t] = (half_t)h;  // same-wave order: visible next iter
  }
  hfin[b * NH_ + t] = h;
  __threadfence();                       // release hfin device-wide
  if (t == 0) atomicAdd(ctr, 1);         // device-scope signal to cls block
}

// ---------------------------------------------------------------------------
extern "C" void kernel_launch(void* const* d_in, const int* in_sizes, int n_in,
                              void* d_out, int out_size, void* d_ws,
                              size_t ws_size, hipStream_t stream) {
  const float* x    = (const float*)d_in[0];
  const float* ts   = (const float*)d_in[1];
  const float* si   = (const float*)d_in[2];
  const float* qp   = (const float*)d_in[3];
  const float* pw   = (const float*)d_in[4];
  const float* pb   = (const float*)d_in[5];
  const float* tlw  = (const float*)d_in[6];
  const float* tlb  = (const float*)d_in[7];
  const float* qw   = (const float*)d_in[8];
  const float* qb   = (const float*)d_in[9];
  const float* kw   = (const float*)d_in[10];
  const float* ow   = (const float*)d_in[12];
  const float* ob   = (const float*)d_in[13];
  const float* wih  = (const float*)d_in[14];
  const float* whh  = (const float*)d_in[15];
  const float* bih  = (const float*)d_in[16];
  const float* bhh  = (const float*)d_in[17];
  const float* stw  = (const float*)d_in[18];
  const float* stb  = (const float*)d_in[19];
  const float* c1w  = (const float*)d_in[20];
  const float* c1b  = (const float*)d_in[21];
  const float* bng  = (const float*)d_in[22];
  const float* bnb  = (const float*)d_in[23];
  const float* c2w  = (const float*)d_in[24];
  const float* c2b  = (const float*)d_in[25];
  const int*   rm   = (const int*)d_in[26];

  float* out = (float*)d_out;

  // workspace layout (floats): qm2 16384 | xmean 2304 | hfin 2048 | ctr 64 |
  // ks_ws 819200 | w_ws 460800 (half2)
  float* W = (float*)d_ws;
  float*   ws_qm2   = W;                 // 16384
  float*   ws_xmean = W + 16384;         // 2304
  float*   ws_hfin  = W + 18688;         // 2048
  int*     ws_ctr   = (int*)(W + 20736); // 1 int (padded to 64)
  float*   ws_ks    = W + 20800;         // 819200
  half2_t* ws_w     = (half2_t*)(W + 20800 + 819200);  // 460800 half2

  hipMemsetAsync(ws_ctr, 0, sizeof(int), stream);
  hipLaunchKernelGGL(k_pre2, dim3(256), dim3(256), 0, stream,
                     qw, kw, qb, qp, pw, pb, tlw, tlb, ts, x, rm,
                     ws_qm2, ws_xmean, ws_ks, ws_w, out);
  hipLaunchKernelGGL(k_attn, dim3(B_ * 16), dim3(512), 0, stream,
                     ws_qm2, ws_ks, ws_w, ws_xmean, ow, ob, out);
  hipLaunchKernelGGL(k_sg, dim3(65), dim3(256), 0, stream,
                     out, x, wih, bih, whh, bhh, si, stw, stb, c1w, c1b,
                     bng, bnb, c2w, c2b, ws_hfin, ws_ctr, out);
}

// Round 11
// 225.069 us; speedup vs baseline: 1.3546x; 1.0444x over previous
//
#include <hip/hip_runtime.h>

#define B_   32
#define L_   200
#define DIM_ 36
#define ET_  128
#define NH_  64
#define SD_  9
#define NC_  2

// element offsets within d_out (float32)
#define O_TE   0
#define O_T1   147456
#define O_LG   294912
#define O_SXG  294976
#define O_SOUT 336448
#define O_QP   377920

typedef __fp16 half_t;
typedef __attribute__((ext_vector_type(2))) __fp16 half2_t;

__device__ __forceinline__ float sigm(float x) { return 1.f / (1.f + expf(-x)); }
__device__ __forceinline__ float fsigm(float x) {
  return __builtin_amdgcn_rcpf(1.f + __expf(-x));
}
__device__ __forceinline__ float ftanh(float x) {
  return 2.f * __builtin_amdgcn_rcpf(1.f + __expf(-2.f * x)) - 1.f;
}
__device__ __forceinline__ half2_t f2h2(float a, float b) {
  return __builtin_amdgcn_cvt_pkrtz(a, b);
}
__device__ __forceinline__ float dot2acc(half2_t w, half2_t h, float acc) {
#if __has_builtin(__builtin_amdgcn_fdot2)
  return __builtin_amdgcn_fdot2(w, h, acc, false);
#else
  return acc + (float)w.x * (float)h.x + (float)w.y * (float)h.y;
#endif
}

// ---------------------------------------------------------------------------
// K1 (k_pre2 v4): R7 v3 + ctr zeroing (replaces the hipMemsetAsync node).
// blocks 0..127 qm2; 128..159 xmean; 160..223 ks_emb pre-swizzled;
// 224..255 W f16.
__global__ __launch_bounds__(256) void k_pre2(
    const float* __restrict__ qw, const float* __restrict__ kw,
    const float* __restrict__ qb, const float* __restrict__ qp,
    const float* __restrict__ pw, const float* __restrict__ pb,
    const float* __restrict__ tlw, const float* __restrict__ tlb,
    const float* __restrict__ ts, const float* __restrict__ x,
    const int* __restrict__ rm,
    float* __restrict__ qm2, float* __restrict__ xmean,
    float* __restrict__ ks_ws, half2_t* __restrict__ w_ws,
    int* __restrict__ ctr, float* __restrict__ out) {
  int blk = blockIdx.x, t = threadIdx.x;
  if (blk < 128) {
    __shared__ float eq[128];
    __shared__ float uq[128];
    int q = blk;
    if (t < 128) {
      float tt = qp[q];
      eq[t] = (t == 0) ? tt * tlw[0] + tlb[0]
                       : __sinf(tt * pw[t - 1] + pb[t - 1]);
    }
    __syncthreads();
    if (t < 128) {
      const float4* qw4 = (const float4*)(qw + (size_t)t * 128);
      float a = qb[t];
      #pragma unroll 8
      for (int c = 0; c < 32; c++) {
        float4 w = qw4[c];
        a += eq[4 * c] * w.x + eq[4 * c + 1] * w.y +
             eq[4 * c + 2] * w.z + eq[4 * c + 3] * w.w;
      }
      uq[t] = a;
    }
    __syncthreads();
    if (t < 128) {
      float a = 0.f;
      #pragma unroll 8
      for (int i = 0; i < 128; i++) a += uq[i] * kw[i * 128 + t];
      qm2[q * 128 + t] = a * 0.088388347648318447f;
      if (q == 0) out[O_QP + t] = qp[t];
    }
    return;
  }
  if (blk < 160) {
    int b = blk - 128;
    if (t < 72) {
      float s = 0.f;
      const float* xb = x + (size_t)b * L_ * 72 + t;
      #pragma unroll 8
      for (int l = 0; l < L_; l++) s += xb[(size_t)l * 72];
      xmean[b * 72 + t] = s * (1.0f / L_);
    }
    if (blk == 128 && t == 72) *ctr = 0;  // replaces hipMemsetAsync; visible
                                          // to k_sg via kernel-end release
    return;
  }
  if (blk < 224) {
    int bb = (blk - 160) >> 1, half = (blk - 160) & 1;
    float tl_w = tlw[0], tl_b = tlb[0];
    const float* tsb = ts + bb * L_;
    float* dst = ks_ws + (size_t)bb * 25600;
    for (int i = half * 12800 + t; i < half * 12800 + 12800; i += 256) {
      int l = i >> 7, j = i & 127;
      float tt = tsb[l];
      float e = (j == 0) ? tt * tl_w + tl_b
                         : __sinf(tt * pw[j - 1] + pb[j - 1]);
      int blkj = (j >> 2) ^ ((l >> 2) & 7);
      dst[(l << 7) + (blkj << 2) + (j & 3)] = e;
    }
    return;
  }
  {
    int bb = blk - 224;
    const float2* xb2 = (const float2*)(x + (size_t)bb * L_ * 72);
    const int* rmb = rm + bb * L_;
    half2_t* wd = w_ws + (size_t)bb * 14400;
    for (int i = t; i < L_ * 72; i += 256) {
      int l = i / 72, c2 = i % 72;
      int seg = c2 / 18, fh = c2 % 18;
      float2 v = xb2[l * 36 + fh];
      float2 o = xb2[l * 36 + 18 + fh];
      float rr = (float)rmb[l];
      float w0, w1;
      if (seg == 0)      { w0 = o.x * v.x;      w1 = o.y * v.y; }
      else if (seg == 1) { w0 = o.x;            w1 = o.y; }
      else if (seg == 2) { w0 = o.x * v.x * rr; w1 = o.y * v.y * rr; }
      else               { w0 = o.x * rr;       w1 = o.y * rr; }
      wd[l * 72 + c2] = f2h2(w0, w1);
    }
  }
}

// ---------------------------------------------------------------------------
// K2 (k_attn v7b): R7 v7 (best measured: 226.4 total) + async-stage W copy —
// the 4 float4/lane global loads of w_ws issue BEFORE P3, ds_write after
// (hides L2 latency under P3's rowmax/exp). Math byte-identical to R7.
__global__ __launch_bounds__(1024, 1) void k_attn(
    const float* __restrict__ qm, const float* __restrict__ ks_ws,
    const half2_t* __restrict__ w_ws,
    const float* __restrict__ xmean, const float* __restrict__ ow,
    const float* __restrict__ ob, float* __restrict__ out) {
  __shared__ __align__(16) char Abuf[103936];   // ks (f32 swz) / wsh2+sums+ofr
  __shared__ __align__(16) float qs[16][128];
  __shared__ __align__(16) float sc[16][200];
  __shared__ __align__(16) float owsh[DIM_][72];
  float*   ksA  = (float*)Abuf;                       // [200][128] swizzled
  half2_t* wsh2 = (half2_t*)Abuf;                     // [200][72] f16x2
  float*   sums = (float*)(Abuf + 57600);             // [4][16][144] partials
  float*   ofr  = (float*)(Abuf + 57600 + 36864);     // [16][144]

  int b = blockIdx.x >> 3;
  int q0 = (blockIdx.x & 7) << 4;
  int tid = threadIdx.x;

  // P0: stage q-tile, ow, and COPY pre-swizzled key embeddings
  const float4* qsrc = (const float4*)(qm + q0 * ET_);
  for (int i = tid; i < 16 * 32; i += 1024) ((float4*)qs)[i] = qsrc[i];
  const float4* owsrc = (const float4*)ow;
  for (int i = tid; i < DIM_ * 18; i += 1024) ((float4*)owsh)[i] = owsrc[i];
  {
    const float4* kssrc = (const float4*)(ks_ws + (size_t)b * 25600);
    for (int i = tid; i < 6400; i += 1024) ((float4*)ksA)[i] = kssrc[i];
  }
  __syncthreads();

  // P2: scores -- 16 waves = 8 q-pairs x 2 l-halves; 2 l per lane
  {
    int w = tid >> 6, lg = tid & 63;
    int qp2 = w >> 1;
    int lh = w & 1;
    float acc[2][2];
    #pragma unroll
    for (int i = 0; i < 2; i++)
      #pragma unroll
      for (int j = 0; j < 2; j++) acc[i][j] = 0.f;
    const float4* ks4 = (const float4*)ksA;
    const float4* qs4 = (const float4*)qs;
    int lbase = 100 * lh + 2 * lg;
    int swz0 = (lbase >> 2) & 7;
    int swz1 = ((lbase + 1) >> 2) & 7;
    #pragma unroll 4
    for (int d4 = 0; d4 < 32; d4++) {
      float4 kv[2];
      {
        int l0c = (lbase < 100 * lh + 100) ? lbase : (100 * lh + 99);
        int l1c = (lbase + 1 < 100 * lh + 100) ? lbase + 1 : (100 * lh + 99);
        kv[0] = ks4[(l0c << 5) + (d4 ^ swz0)];
        kv[1] = ks4[(l1c << 5) + (d4 ^ swz1)];
      }
      #pragma unroll
      for (int i = 0; i < 2; i++) {
        float4 qv = qs4[(2 * qp2 + i) * 32 + d4];
        #pragma unroll
        for (int j = 0; j < 2; j++)
          acc[i][j] += qv.x * kv[j].x + qv.y * kv[j].y +
                       qv.z * kv[j].z + qv.w * kv[j].w;
      }
    }
    if (2 * lg < 100) {
      #pragma unroll
      for (int i = 0; i < 2; i++) {
        float2 v = {acc[i][0], acc[i][1]};
        *((float2*)(&sc[2 * qp2 + i][lbase])) = v;
      }
    }
  }
  __syncthreads();

  // P4a: ISSUE W loads to registers (latency hides under P3)
  float4 wr0, wr1, wr2, wr3;
  {
    const float4* wsrc = (const float4*)(w_ws + (size_t)b * 14400);
    wr0 = wsrc[tid];
    wr1 = wsrc[tid + 1024];
    wr2 = wsrc[tid + 2048];
    if (tid < 528) wr3 = wsrc[tid + 3072];
  }

  // P3: rowmax + exp in place (64 lanes per q-row)
  {
    int qi = tid >> 6, li = tid & 63;
    float m = -1e30f;
    for (int l = li; l < L_; l += 64) m = fmaxf(m, sc[qi][l]);
    #pragma unroll
    for (int off = 32; off >= 1; off >>= 1) m = fmaxf(m, __shfl_xor(m, off));
    for (int l = li; l < L_; l += 64) sc[qi][l] = __expf(sc[qi][l] - m);
  }

  // P4b: write the staged W f16 into the (dead) ks region
  {
    ((float4*)wsh2)[tid]        = wr0;
    ((float4*)wsh2)[tid + 1024] = wr1;
    ((float4*)wsh2)[tid + 2048] = wr2;
    if (tid < 528) ((float4*)wsh2)[tid + 3072] = wr3;
  }
  __syncthreads();

  // P5: weight sums, l split 4 ways (partials in sums[4][16][144])
  {
    int quarter = tid >> 8, tt = tid & 255;
    int qi = tt >> 4, li = tt & 15;
    int l0 = quarter * 50;
    float accA[8], accB[8];
    #pragma unroll
    for (int k = 0; k < 8; k++) { accA[k] = 0.f; accB[k] = 0.f; }
    const float4* wA = (const float4*)wsh2;
    #pragma unroll 2
    for (int l = l0; l < l0 + 50; l++) {
      float ev = sc[qi][l];
      float4 wa = wA[l * 18 + li];
      union { float f; half2_t h; } u0, u1, u2, u3;
      u0.f = wa.x; u1.f = wa.y; u2.f = wa.z; u3.f = wa.w;
      accA[0] += ev * (float)u0.h.x; accA[1] += ev * (float)u0.h.y;
      accA[2] += ev * (float)u1.h.x; accA[3] += ev * (float)u1.h.y;
      accA[4] += ev * (float)u2.h.x; accA[5] += ev * (float)u2.h.y;
      accA[6] += ev * (float)u3.h.x; accA[7] += ev * (float)u3.h.y;
      if (li < 2) {
        float4 wb = wA[l * 18 + 16 + li];
        union { float f; half2_t h; } b0, b1, b2, b3;
        b0.f = wb.x; b1.f = wb.y; b2.f = wb.z; b3.f = wb.w;
        accB[0] += ev * (float)b0.h.x; accB[1] += ev * (float)b0.h.y;
        accB[2] += ev * (float)b1.h.x; accB[3] += ev * (float)b1.h.y;
        accB[4] += ev * (float)b2.h.x; accB[5] += ev * (float)b2.h.y;
        accB[6] += ev * (float)b3.h.x; accB[7] += ev * (float)b3.h.y;
      }
    }
    float* sq = sums + quarter * 2304 + qi * 144;
    float4* sA = (float4*)(sq + 8 * li);
    sA[0] = make_float4(accA[0], accA[1], accA[2], accA[3]);
    sA[1] = make_float4(accA[4], accA[5], accA[6], accA[7]);
    if (li < 2) {
      float4* sB = (float4*)(sq + 128 + 8 * li);
      sB[0] = make_float4(accB[0], accB[1], accB[2], accB[3]);
      sB[1] = make_float4(accB[4], accB[5], accB[6], accB[7]);
    }
  }
  __syncthreads();

  // P6: combine quarters + divisions + uniform-mean fallback
  const float* xm = xmean + b * 72;
  for (int idx = tid; idx < 16 * DIM_; idx += 1024) {
    int qq = idx / DIM_, j = idx % DIM_;
    const float* s0 = sums + qq * 144;
    const float* s1 = s0 + 2304;
    const float* s2 = s1 + 2304;
    const float* s3 = s2 + 2304;
    float numA = (s0[j] + s1[j]) + (s2[j] + s3[j]);
    float denA = (s0[36 + j] + s1[36 + j]) + (s2[36 + j] + s3[36 + j]);
    float numB = (s0[72 + j] + s1[72 + j]) + (s2[72 + j] + s3[72 + j]);
    float denB = (s0[108 + j] + s1[108 + j]) + (s2[108 + j] + s3[108 + j]);
    float al, ah, bl, bh;
    if (denA > 0.f) { al = numA / denA; ah = 1.f; }
    else            { al = xm[j];       ah = xm[36 + j]; }
    if (denB > 0.f) { bl = numB / denB; bh = 1.f; }
    else            { bl = xm[j];       bh = xm[36 + j]; }
    float* oq = ofr + qq * 144;
    oq[j] = al;      oq[36 + j] = ah;
    oq[72 + j] = bl; oq[108 + j] = bh;
  }
  __syncthreads();

  // P7: output projection (float4 dots)
  for (int idx = tid; idx < 16 * 72; idx += 1024) {
    int qq = idx / 72, t = idx % 72;
    int v = t / DIM_, i2 = t % DIM_;
    const float4* o4 = (const float4*)(ofr + qq * 144 + v * 72);
    const float4* w4 = (const float4*)(owsh[i2]);
    float a = ob[i2];
    #pragma unroll
    for (int d4 = 0; d4 < 18; d4++) {
      float4 ov = o4[d4], wv = w4[d4];
      a += ov.x * wv.x + ov.y * wv.y + ov.z * wv.z + ov.w * wv.w;
    }
    size_t off = ((size_t)b * ET_ + q0 + qq) * DIM_ + i2;
    out[(v == 0 ? O_TE : O_T1) + off] = a;
  }
}

// ---------------------------------------------------------------------------
// K3 (k_sg v10, R5/R7-exact — the scan is FROZEN): blocks 0..31 sout+sxg;
// 32..63 GRU v6 single-scan + release; block 64 classifier with LDS weight
// prefetch hidden under the spin window.
__global__ __launch_bounds__(256, 1) void k_sg(
    const float* __restrict__ out_ro, const float* __restrict__ x,
    const float* __restrict__ wih, const float* __restrict__ bih,
    const float* __restrict__ whh, const float* __restrict__ bhh,
    const float* __restrict__ si, const float* __restrict__ stw,
    const float* __restrict__ stb, const float* __restrict__ c1w,
    const float* __restrict__ c1b, const float* __restrict__ bng,
    const float* __restrict__ bnb, const float* __restrict__ c2w,
    const float* __restrict__ c2b,
    float* __restrict__ hfin, int* __restrict__ ctr,
    float* __restrict__ out) {
  __shared__ __align__(16) float ote_s[ET_][DIM_];  // 18 KB
  __shared__ float gis[ET_][3 * NH_];               // 96 KB (gru/sxg/cls stage)
  __shared__ __align__(16) half2_t hpk[NH_ / 2];    // packed f16 h
  int blk = blockIdx.x, t = threadIdx.x;

  if (blk >= 64) {
    // ---- classifier block ----
    float* base = &gis[0][0];
    float (*cin)[72] = (float(*)[72])(base);              // [32][72]
    float (*z1)[72]  = (float(*)[72])(base + 2304);       // [32][72]
    float (*zg)[72]  = (float(*)[72])(base + 4608);       // [32][72]
    float* c1wt = base + 6912;                            // [72][72] transposed
    float* c2ws = base + 6912 + 5184;                     // [2][72]
    float* bngs = c2ws + 144;                             // [72]
    float* bnbs = bngs + 72;                              // [72]
    for (int idx = t; idx < 72 * 72; idx += 256) {
      int j = idx / 72, d = idx % 72;
      c1wt[d * 72 + j] = c1w[idx];
    }
    for (int idx = t; idx < NC_ * 72; idx += 256) c2ws[idx] = c2w[idx];
    if (t < 72) { bngs[t] = bng[t]; bnbs[t] = bnb[t]; }
    for (int idx = t; idx < B_ * 8; idx += 256) {
      int b = idx / 8, j = idx % 8;
      float acc = stb[j];
      #pragma unroll
      for (int d = 0; d < SD_; d++) acc += si[b * SD_ + d] * stw[j * SD_ + d];
      cin[b][NH_ + j] = acc;
    }
    __syncthreads();
    if (t == 0) {
      while (__hip_atomic_load(ctr, __ATOMIC_ACQUIRE,
                               __HIP_MEMORY_SCOPE_AGENT) < 32)
        __builtin_amdgcn_s_sleep(8);
    }
    __syncthreads();
    for (int idx = t; idx < B_ * NH_; idx += 256)
      cin[idx / NH_][idx % NH_] = hfin[idx];
    __syncthreads();
    for (int idx = t; idx < B_ * 72; idx += 256) {
      int b = idx / 72, j = idx % 72;
      float acc = c1b[j];
      #pragma unroll 8
      for (int d = 0; d < 72; d++) acc += cin[b][d] * c1wt[d * 72 + j];
      z1[b][j] = acc;
    }
    __syncthreads();
    if (t < 72) {
      float mu = 0.f;
      for (int b = 0; b < B_; b++) mu += z1[b][t];
      mu *= (1.f / B_);
      float vv = 0.f;
      for (int b = 0; b < B_; b++) { float d = z1[b][t] - mu; vv += d * d; }
      vv *= (1.f / B_);
      float inv = 1.f / sqrtf(vv + 1e-5f);
      float g = bngs[t], bb = bnbs[t];
      for (int b = 0; b < B_; b++) {
        float zn = (z1[b][t] - mu) * inv * g + bb;
        zg[b][t] = 0.5f * zn * (1.f + erff(zn * 0.70710678118654752f));
      }
    }
    __syncthreads();
    for (int idx = t; idx < B_ * NC_; idx += 256) {
      int b = idx / NC_, c = idx % NC_;
      float acc = c2b[c];
      #pragma unroll 8
      for (int d = 0; d < 72; d++) acc += zg[b][d] * c2ws[c * 72 + d];
      out[O_LG + idx] = acc;
    }
    return;
  }

  if (blk < 32) {
    int b = blk;
    float* sxs = (float*)gis;  // [200][76]
    const float4* osrc = (const float4*)(out_ro + O_TE + (size_t)b * ET_ * DIM_);
    for (int idx = t; idx < ET_ * 9; idx += 256)
      ((float4*)&ote_s[0][0])[idx] = osrc[idx];
    const float4* xsrc = (const float4*)(x + (size_t)b * L_ * 72);
    for (int idx = t; idx < L_ * 18; idx += 256) {
      int l = idx / 18, c = idx % 18;
      ((float4*)&sxs[l * 76])[c] = xsrc[idx];
    }
    __syncthreads();
    for (int idx = t; idx < DIM_ * DIM_; idx += 256) {
      int d = idx / DIM_, e = idx % DIM_;
      float s = 0.f;
      #pragma unroll 8
      for (int q = 0; q < ET_; q++) s += ote_s[q][d] * ote_s[q][e];
      out[O_SOUT + (size_t)b * DIM_ * DIM_ + idx] = sigm(s);
    }
    for (int idx = t; idx < DIM_ * DIM_; idx += 256) {
      int d = idx / DIM_, e = idx % DIM_;
      float s = 0.f;
      #pragma unroll 8
      for (int l = 0; l < L_; l++) s += sxs[l * 76 + d] * sxs[l * 76 + e];
      out[O_SXG + (size_t)b * DIM_ * DIM_ + idx] = rintf(sigm(s));
    }
    return;
  }

  int b = blk - 32;
  const float* ote = out_ro + O_TE;
  const float4* osrc = (const float4*)(ote + (size_t)b * ET_ * DIM_);
  for (int idx = t; idx < ET_ * DIM_ / 4; idx += 256)
    ((float4*)&ote_s[0][0])[idx] = osrc[idx];
  __syncthreads();

  // phase 1: gi[q][t] = bih[t] (+bhh[t] for r/z rows) + ote[q]·wih[t]
  if (t < 3 * NH_) {
    float wv[DIM_];
    const float* wrow = wih + (size_t)t * DIM_;
    #pragma unroll
    for (int d = 0; d < DIM_; d++) wv[d] = wrow[d];
    float bi = bih[t] + ((t < 2 * NH_) ? bhh[t] : 0.f);
    for (int q = 0; q < ET_; q++) {
      const float4* xr = (const float4*)ote_s[q];
      float a = bi;
      #pragma unroll
      for (int c = 0; c < 9; c++) {
        float4 xv = xr[c];
        a += xv.x * wv[4 * c] + xv.y * wv[4 * c + 1] +
             xv.z * wv[4 * c + 2] + xv.w * wv[4 * c + 3];
      }
      gis[q][t] = a;
    }
  }
  __syncthreads();
  if (t >= 64) return;  // waves 1..3 exit; wave 0 scans barrier-free

  // pack whh rows t, 64+t, 128+t into f16 (32 half2 each = 96 VGPRs)
  half2_t wr[32], wz[32], wn[32];
  {
    const float2* r0 = (const float2*)(whh + (size_t)t * NH_);
    const float2* r1 = (const float2*)(whh + (size_t)(NH_ + t) * NH_);
    const float2* r2 = (const float2*)(whh + (size_t)(2 * NH_ + t) * NH_);
    #pragma unroll
    for (int c = 0; c < 32; c++) {
      float2 a = r0[c], bb = r1[c], cc = r2[c];
      wr[c] = f2h2(a.x, a.y);
      wz[c] = f2h2(bb.x, bb.y);
      wn[c] = f2h2(cc.x, cc.y);
    }
  }
  float bh_n = bhh[2 * NH_ + t];

  float h = 0.f;
  ((half_t*)hpk)[t] = (half_t)0.f;
  for (int q = 0; q < ET_; q++) {
    float gi_r = gis[q][t];
    float gi_z = gis[q][NH_ + t];
    float gi_n = gis[q][2 * NH_ + t];
    float ar = 0.f, az = 0.f, an = 0.f;
    const float4* hp4 = (const float4*)hpk;
    #pragma unroll
    for (int c4 = 0; c4 < 8; c4++) {
      float4 hv = hp4[c4];  // broadcast b128 (all lanes same addr)
      union { float f; half2_t h; } u0, u1, u2, u3;
      u0.f = hv.x; u1.f = hv.y; u2.f = hv.z; u3.f = hv.w;
      int c = c4 * 4;
      ar = dot2acc(wr[c + 0], u0.h, ar);
      az = dot2acc(wz[c + 0], u0.h, az);
      an = dot2acc(wn[c + 0], u0.h, an);
      ar = dot2acc(wr[c + 1], u1.h, ar);
      az = dot2acc(wz[c + 1], u1.h, az);
      an = dot2acc(wn[c + 1], u1.h, an);
      ar = dot2acc(wr[c + 2], u2.h, ar);
      az = dot2acc(wz[c + 2], u2.h, az);
      an = dot2acc(wn[c + 2], u2.h, an);
      ar = dot2acc(wr[c + 3], u3.h, ar);
      az = dot2acc(wz[c + 3], u3.h, az);
      an = dot2acc(wn[c + 3], u3.h, an);
    }
    float r = fsigm(gi_r + ar);
    float z = fsigm(gi_z + az);
    float n = ftanh(gi_n + r * (an + bh_n));
    h = n + z * (h - n);
    ((half_t*)hpk)[t] = (half_t)h;  // same-wave order: visible next iter
  }
  hfin[b * NH_ + t] = h;
  __threadfence();                       // release hfin device-wide
  if (t == 0) atomicAdd(ctr, 1);         // device-scope signal to cls block
}

// ---------------------------------------------------------------------------
extern "C" void kernel_launch(void* const* d_in, const int* in_sizes, int n_in,
                              void* d_out, int out_size, void* d_ws,
                              size_t ws_size, hipStream_t stream) {
  const float* x    = (const float*)d_in[0];
  const float* ts   = (const float*)d_in[1];
  const float* si   = (const float*)d_in[2];
  const float* qp   = (const float*)d_in[3];
  const float* pw   = (const float*)d_in[4];
  const float* pb   = (const float*)d_in[5];
  const float* tlw  = (const float*)d_in[6];
  const float* tlb  = (const float*)d_in[7];
  const float* qw   = (const float*)d_in[8];
  const float* qb   = (const float*)d_in[9];
  const float* kw   = (const float*)d_in[10];
  const float* ow   = (const float*)d_in[12];
  const float* ob   = (const float*)d_in[13];
  const float* wih  = (const float*)d_in[14];
  const float* whh  = (const float*)d_in[15];
  const float* bih  = (const float*)d_in[16];
  const float* bhh  = (const float*)d_in[17];
  const float* stw  = (const float*)d_in[18];
  const float* stb  = (const float*)d_in[19];
  const float* c1w  = (const float*)d_in[20];
  const float* c1b  = (const float*)d_in[21];
  const float* bng  = (const float*)d_in[22];
  const float* bnb  = (const float*)d_in[23];
  const float* c2w  = (const float*)d_in[24];
  const float* c2b  = (const float*)d_in[25];
  const int*   rm   = (const int*)d_in[26];

  float* out = (float*)d_out;

  // workspace layout (floats): qm2 16384 | xmean 2304 | hfin 2048 | ctr 64 |
  // ks_ws 819200 | w_ws 460800 (half2)
  float* W = (float*)d_ws;
  float*   ws_qm2   = W;                 // 16384
  float*   ws_xmean = W + 16384;         // 2304
  float*   ws_hfin  = W + 18688;         // 2048
  int*     ws_ctr   = (int*)(W + 20736); // 1 int (padded to 64)
  float*   ws_ks    = W + 20800;         // 819200
  half2_t* ws_w     = (half2_t*)(W + 20800 + 819200);  // 460800 half2

  hipLaunchKernelGGL(k_pre2, dim3(256), dim3(256), 0, stream,
                     qw, kw, qb, qp, pw, pb, tlw, tlb, ts, x, rm,
                     ws_qm2, ws_xmean, ws_ks, ws_w, ws_ctr, out);
  hipLaunchKernelGGL(k_attn, dim3(B_ * 8), dim3(1024), 0, stream,
                     ws_qm2, ws_ks, ws_w, ws_xmean, ow, ob, out);
  hipLaunchKernelGGL(k_sg, dim3(65), dim3(256), 0, stream,
                     out, x, wih, bih, whh, bhh, si, stw, stb, c1w, c1b,
                     bng, bnb, c2w, c2b, ws_hfin, ws_ctr, out);
}